// Round 9
// baseline (204.783 us; speedup 1.0000x reference)
//
#include <hip/hip_runtime.h>

#define N_NODES 50000
#define N_EDGES 600000
#define CH 128
#define NUM_GRAPHS 512
#define OUT_CH 64
// padded bucket stride (max degree safety: Poisson(12), P(>=64) ~ 0)
#define DSH 6
#define DSTRIDE 64
// counter stride: one 64B line per node to kill same-line atomic serialization
#define CSH 4

typedef unsigned int uint32;
typedef __attribute__((ext_vector_type(8))) short short8;
typedef __attribute__((ext_vector_type(4))) float floatx4;

// pack two fp32 -> bf16x2 (RNE), lo = first channel
__device__ __forceinline__ uint32 bfpack(float a, float b) {
    uint32 ua = __builtin_bit_cast(uint32, a);
    uint32 ub = __builtin_bit_cast(uint32, b);
    ua = (ua + 0x7fffu + ((ua >> 16) & 1u)) >> 16;
    ub = (ub + 0x7fffu + ((ub >> 16) & 1u)) >> 16;
    return (ub << 16) | ua;
}
__device__ __forceinline__ unsigned short bfr(float f) {
    uint32 u = __builtin_bit_cast(uint32, f);
    u = (u + 0x7fffu + ((u >> 16) & 1u)) >> 16;
    return (unsigned short)u;
}
__device__ __forceinline__ float bf_lo(uint32 v) {
    return __builtin_bit_cast(float, v << 16);
}
__device__ __forceinline__ float bf_hi(uint32 v) {
    return __builtin_bit_cast(float, v & 0xffff0000u);
}

// ---------------- prep: zero padded cur + W1,W2 -> bf16 transposed (Wt[c][k]) --------
// grid 3125 x 256 = 800000 threads
__global__ void k_prep(const float* __restrict__ W1, const float* __restrict__ W2,
                       unsigned short* __restrict__ W1t, unsigned short* __restrict__ W2t,
                       int* __restrict__ cur) {
    int idx = blockIdx.x * 256 + threadIdx.x;
    if (idx < (N_NODES << CSH)) cur[idx] = 0;
    if (idx < 32768) {
        int mat = idx >> 14;
        int rem = idx & 16383;
        int k = rem >> 7, c = rem & 127;
        const float* W = mat ? W2 : W1;
        unsigned short* Wt = mat ? W2t : W1t;
        Wt[c * 128 + k] = bfr(W[k * 128 + c]);
    }
}

// ---------------- padded-CSR build: one pass, no scan ----------------
// 1 edge/thread (2344 blocks -> ~37 waves/CU); counters line-padded.
__global__ void k_fill_pad(const int* __restrict__ src, const int* __restrict__ dst,
                           int* __restrict__ cur, int* __restrict__ srcs) {
    int e = blockIdx.x * 256 + threadIdx.x;
    if (e < N_EDGES) {
        int s = src[e];
        int d = dst[e];
        int p = atomicAdd(&cur[d << CSH], 1);
        srcs[(d << DSH) + p] = s;
    }
}

// ---------------- MFMA GEMM: outb[N,128](bf16) = bf16(dinv * (A @ W)) ----------------
// A: fp32 [N][128] (AF32=true, packs to bf16 during staging) or bf16 [N][128].
// Wt: bf16 transposed [col][k]. 256 thr = 4 waves, block tile 128x128;
// wave = 2 row-tiles x 8 col-tiles of 16x16x32 MFMA.
// Layouts (verified, learn_hip m89/m91/m120): A-frag [m=lane&15][k=quad*8+j],
// B-frag [n=lane&15][k=quad*8+j] (from Wt), C/D row=quad*4+reg, col=lane&15.
template <bool AF32>
__global__ __launch_bounds__(256, 2) void k_gemm(const void* __restrict__ Av,
                                                 const unsigned short* __restrict__ Wt,
                                                 const int* __restrict__ cur,
                                                 unsigned short* __restrict__ outb) {
    __shared__ __align__(16) unsigned short as_[128][136];  // +8 pad: stride 272B
    __shared__ __align__(16) unsigned short bs[128][136];
    int tid = threadIdx.x;
    int row0 = blockIdx.x * 128;

    #pragma unroll
    for (int it = 0; it < 8; ++it) {            // A tile: 128 rows x 16 segs x 8 ch
        int idx = it * 256 + tid;
        int r = idx >> 4, seg = idx & 15;
        int gr = min(row0 + r, N_NODES - 1);
        if (AF32) {
            const float4* ap = (const float4*)((const float*)Av + (size_t)gr * 128 + seg * 8);
            float4 v0 = ap[0], v1 = ap[1];
            uint4 pk;
            pk.x = bfpack(v0.x, v0.y); pk.y = bfpack(v0.z, v0.w);
            pk.z = bfpack(v1.x, v1.y); pk.w = bfpack(v1.z, v1.w);
            *(uint4*)&as_[r][seg * 8] = pk;
        } else {
            *(uint4*)&as_[r][seg * 8] =
                *(const uint4*)((const unsigned short*)Av + (size_t)gr * 128 + seg * 8);
        }
    }
    #pragma unroll
    for (int it = 0; it < 8; ++it) {            // Wt tile: 128 cols x 256B
        int idx = it * 256 + tid;
        int c = idx >> 4, seg = idx & 15;
        *(uint4*)&bs[c][seg * 8] = *(const uint4*)&Wt[c * 128 + seg * 8];
    }
    __syncthreads();

    int w = tid >> 6, lane = tid & 63, q = lane >> 4, m = lane & 15;
    int q8 = q * 8;
    floatx4 acc[2][8];
    #pragma unroll
    for (int rt = 0; rt < 2; ++rt)
        #pragma unroll
        for (int ct = 0; ct < 8; ++ct) {
            floatx4 z = {0.f, 0.f, 0.f, 0.f};
            acc[rt][ct] = z;
        }

    #pragma unroll
    for (int kc = 0; kc < 128; kc += 32) {
        short8 a0 = *(const short8*)&as_[w * 32 + m][kc + q8];
        short8 a1 = *(const short8*)&as_[w * 32 + 16 + m][kc + q8];
        #pragma unroll
        for (int ct = 0; ct < 8; ++ct) {
            short8 b = *(const short8*)&bs[ct * 16 + m][kc + q8];
            acc[0][ct] = __builtin_amdgcn_mfma_f32_16x16x32_bf16(a0, b, acc[0][ct], 0, 0, 0);
            acc[1][ct] = __builtin_amdgcn_mfma_f32_16x16x32_bf16(a1, b, acc[1][ct], 0, 0, 0);
        }
    }

    #pragma unroll
    for (int rt = 0; rt < 2; ++rt) {
        #pragma unroll
        for (int i = 0; i < 4; ++i) {
            int gr = row0 + w * 32 + rt * 16 + q * 4 + i;
            if (gr < N_NODES) {
                float sc = rsqrtf((float)(cur[gr << CSH] + 1));
                #pragma unroll
                for (int ct = 0; ct < 8; ++ct) {
                    outb[(size_t)gr * 128 + ct * 16 + m] = bfr(acc[rt][ct][i] * sc);
                }
            }
        }
    }
}

// ---------------- aggregation: padded buckets, pure bf16 gathers ----------------
// a[d] = sum_{s in bucket} hb[s] + hb[d];  act = relu(dn*a + b)
// BF16OUT: bf16 (layer1 -> gemm2 input); else fp32 (layer2 -> pool).
template <bool BF16OUT>
__global__ __launch_bounds__(256) void k_agg(const uint32* __restrict__ hb,
                                             const int* __restrict__ cnt_arr,
                                             const int* __restrict__ srcs,
                                             const float* __restrict__ bias,
                                             void* __restrict__ outv) {
    int node = __builtin_amdgcn_readfirstlane(blockIdx.x * 4 + (threadIdx.x >> 6));
    int lane = threadIdx.x & 63;

    int cnt = cnt_arr[node << CSH];
    float dn = rsqrtf((float)(cnt + 1));
    uint32 vs = hb[node * 64 + lane];       // self-loop: bf16(dinv[n]*h[n])
    float ax = bf_lo(vs), ay = bf_hi(vs);

    int start = node << DSH;
    int last = start + cnt - 1;
    for (int j = 0; j < cnt; j += 8) {
        int i0 = start + j;
        int i1 = min(i0 + 1, last);
        int i2 = min(i0 + 2, last);
        int i3 = min(i0 + 3, last);
        int i4 = min(i0 + 4, last);
        int i5 = min(i0 + 5, last);
        int i6 = min(i0 + 6, last);
        int i7 = min(i0 + 7, last);
        int s0 = srcs[i0], s1 = srcs[i1], s2 = srcs[i2], s3 = srcs[i3];
        int s4 = srcs[i4], s5 = srcs[i5], s6 = srcs[i6], s7 = srcs[i7];
        uint32 v0 = hb[s0 * 64 + lane];
        uint32 v1 = hb[s1 * 64 + lane];
        uint32 v2 = hb[s2 * 64 + lane];
        uint32 v3 = hb[s3 * 64 + lane];
        uint32 v4 = hb[s4 * 64 + lane];
        uint32 v5 = hb[s5 * 64 + lane];
        uint32 v6 = hb[s6 * 64 + lane];
        uint32 v7 = hb[s7 * 64 + lane];
        int rem = cnt - j;
        v1 = (rem > 1) ? v1 : 0u;
        v2 = (rem > 2) ? v2 : 0u;
        v3 = (rem > 3) ? v3 : 0u;
        v4 = (rem > 4) ? v4 : 0u;
        v5 = (rem > 5) ? v5 : 0u;
        v6 = (rem > 6) ? v6 : 0u;
        v7 = (rem > 7) ? v7 : 0u;
        ax += bf_lo(v0); ay += bf_hi(v0);
        ax += bf_lo(v1); ay += bf_hi(v1);
        ax += bf_lo(v2); ay += bf_hi(v2);
        ax += bf_lo(v3); ay += bf_hi(v3);
        ax += bf_lo(v4); ay += bf_hi(v4);
        ax += bf_lo(v5); ay += bf_hi(v5);
        ax += bf_lo(v6); ay += bf_hi(v6);
        ax += bf_lo(v7); ay += bf_hi(v7);
    }
    float2 b = ((const float2*)bias)[lane];
    ax = fmaxf(ax * dn + b.x, 0.f);
    ay = fmaxf(ay * dn + b.y, 0.f);
    if (BF16OUT) ((uint32*)outv)[node * 64 + lane] = bfpack(ax, ay);
    else         ((float2*)outv)[node * 64 + lane] = make_float2(ax, ay);
}

// ---------------- fused mean-pool + linear (batch is sorted) ----------------
__global__ __launch_bounds__(256) void k_pool_linear(const float* __restrict__ h,
                                                     const int* __restrict__ batch,
                                                     const float* __restrict__ Wl,
                                                     const float* __restrict__ bl,
                                                     float* __restrict__ out) {
    __shared__ int sb[2];
    __shared__ float4 sacc[256];
    __shared__ float xr[CH];
    __shared__ float po[4][OUT_CH];
    int g = blockIdx.x;
    int tid = threadIdx.x;
    if (tid < 2) {
        int target = g + tid;
        int lo = 0, hi = N_NODES;
        while (lo < hi) {
            int mid = (lo + hi) >> 1;
            if (batch[mid] < target) lo = mid + 1; else hi = mid;
        }
        sb[tid] = lo;
    }
    __syncthreads();
    int lo = sb[0], hi = sb[1];
    int q = tid & 31;   // channel quad
    int r = tid >> 5;   // row phase 0..7
    const float4* h4 = (const float4*)h;
    float4 acc = make_float4(0.f, 0.f, 0.f, 0.f);
    for (int i = lo + r; i < hi; i += 8) {
        float4 v = h4[(size_t)i * 32 + q];
        acc.x += v.x; acc.y += v.y; acc.z += v.z; acc.w += v.w;
    }
    sacc[tid] = acc;
    __syncthreads();
    if (r == 0) {
        #pragma unroll
        for (int p = 1; p < 8; ++p) {
            float4 t = sacc[q + p * 32];
            acc.x += t.x; acc.y += t.y; acc.z += t.z; acc.w += t.w;
        }
        float inv = 1.f / (float)((hi - lo) > 0 ? (hi - lo) : 1);
        xr[q * 4 + 0] = acc.x * inv;
        xr[q * 4 + 1] = acc.y * inv;
        xr[q * 4 + 2] = acc.z * inv;
        xr[q * 4 + 3] = acc.w * inv;
    }
    __syncthreads();
    int c = tid & 63;
    int kh = tid >> 6;
    float o = 0.f;
    #pragma unroll 8
    for (int k = kh * 32; k < kh * 32 + 32; ++k) o += xr[k] * Wl[k * OUT_CH + c];
    po[kh][c] = o;
    __syncthreads();
    if (tid < OUT_CH) {
        float v = bl[tid] + po[0][tid] + po[1][tid] + po[2][tid] + po[3][tid];
        out[g * OUT_CH + tid] = v;
    }
}

extern "C" void kernel_launch(void* const* d_in, const int* in_sizes, int n_in,
                              void* d_out, int out_size, void* d_ws, size_t ws_size,
                              hipStream_t stream) {
    const float* x    = (const float*)d_in[0];
    const float* W1   = (const float*)d_in[1];
    const float* b1   = (const float*)d_in[2];
    const float* W2   = (const float*)d_in[3];
    const float* b2   = (const float*)d_in[4];
    const float* Wlin = (const float*)d_in[5];
    const float* blin = (const float*)d_in[6];
    const int* ei     = (const int*)d_in[7];
    const int* batch  = (const int*)d_in[8];
    const int* esrc = ei;
    const int* edst = ei + N_EDGES;
    float* out = (float*)d_out;

    char* w = (char*)d_ws;
    size_t o = 0;
    float* hA            = (float*)(w + o);          o += (size_t)N_NODES * CH * 4;      // fp32 agg2 out
    unsigned short* hb   = (unsigned short*)(w + o); o += (size_t)N_NODES * CH * 2;      // bf16 prescaled gemm out
    uint32* habf         = (uint32*)(w + o);         o += (size_t)N_NODES * 64 * 4;      // bf16 agg1 out
    unsigned short* W1t  = (unsigned short*)(w + o); o += 16384 * 2;
    unsigned short* W2t  = (unsigned short*)(w + o); o += 16384 * 2;
    int* srcs            = (int*)(w + o);            o += (size_t)N_NODES * DSTRIDE * 4; // padded buckets
    int* cur             = (int*)(w + o);            o += (size_t)(N_NODES << CSH) * 4;  // line-padded counters
    (void)ws_size; (void)in_sizes; (void)n_in; (void)out_size;

    dim3 b256(256);
    k_prep<<<dim3(((N_NODES << CSH) + 255) / 256), b256, 0, stream>>>(W1, W2, W1t, W2t, cur);
    k_fill_pad<<<dim3((N_EDGES + 255) / 256), b256, 0, stream>>>(esrc, edst, cur, srcs);

    dim3 gG((N_NODES + 127) / 128);   // 391 blocks
    dim3 gA(N_NODES / 4);             // 12500 blocks, one wave64 per node
    k_gemm<true><<<gG, b256, 0, stream>>>(x, W1t, cur, hb);
    k_agg<true><<<gA, b256, 0, stream>>>((const uint32*)hb, cur, srcs, b1, habf);
    k_gemm<false><<<gG, b256, 0, stream>>>(habf, W2t, cur, hb);
    k_agg<false><<<gA, b256, 0, stream>>>((const uint32*)hb, cur, srcs, b2, hA);
    k_pool_linear<<<dim3(NUM_GRAPHS), b256, 0, stream>>>(hA, batch, Wlin, blin, out);
}